// Round 1
// baseline (848.498 us; speedup 1.0000x reference)
//
#include <hip/hip_runtime.h>
#include <hip/hip_bf16.h>
#include <cstdint>

#define DEV __device__ __forceinline__

typedef __bf16 bf16_t;
typedef __bf16 bf16x8 __attribute__((ext_vector_type(8)));
typedef __bf16 bf16x4 __attribute__((ext_vector_type(4)));
typedef float  f32x4  __attribute__((ext_vector_type(4)));

constexpr int Bb = 2, Ss = 2048, Dd = 1024, Hh = 16, DKk = 64, FFf = 4096;
constexpr int TOK = Bb * Ss;          // 4096 tokens
constexpr float LN_EPS = 1e-6f;

// ---- async global->LDS, 16B per lane (wave-uniform base + lane*16) ----
DEV void g2l16(const void* g, void* l) {
    __builtin_amdgcn_global_load_lds(
        (const __attribute__((address_space(1))) unsigned int*)g,
        (__attribute__((address_space(3))) unsigned int*)l, 16, 0, 0);
}

// =====================  weight fp32 [K,N] -> bf16 [N,K]  =====================
__global__ __launch_bounds__(256)
void transpose_cast(const float* __restrict__ src, bf16_t* __restrict__ dst,
                    int K, int N) {
    __shared__ float t[32][33];
    const int tx = threadIdx.x & 31, ty = threadIdx.x >> 5;
    const int n0 = blockIdx.x * 32, k0 = blockIdx.y * 32;
#pragma unroll
    for (int i = 0; i < 4; ++i)
        t[ty + 8 * i][tx] = src[(size_t)(k0 + ty + 8 * i) * N + n0 + tx];
    __syncthreads();
#pragma unroll
    for (int i = 0; i < 4; ++i)
        dst[(size_t)(n0 + ty + 8 * i) * K + k0 + tx] = (bf16_t)t[tx][ty + 8 * i];
}

// =====================  LayerNorm fp32 -> bf16  =====================
__global__ __launch_bounds__(256)
void ln_fwd(const float* __restrict__ x, const float* __restrict__ g,
            const float* __restrict__ b, bf16_t* __restrict__ out) {
    __shared__ float red[8];
    const int row = blockIdx.x, tid = threadIdx.x;
    const float4 v = ((const float4*)(x + (size_t)row * Dd))[tid];
    float s  = v.x + v.y + v.z + v.w;
    float sq = v.x * v.x + v.y * v.y + v.z * v.z + v.w * v.w;
#pragma unroll
    for (int o = 32; o; o >>= 1) { s += __shfl_xor(s, o); sq += __shfl_xor(sq, o); }
    if ((tid & 63) == 0) { red[tid >> 6] = s; red[4 + (tid >> 6)] = sq; }
    __syncthreads();
    s  = red[0] + red[1] + red[2] + red[3];
    sq = red[4] + red[5] + red[6] + red[7];
    const float mean = s * (1.f / Dd);
    const float var  = sq * (1.f / Dd) - mean * mean;
    const float rs   = rsqrtf(var + LN_EPS);
    const float4 gv = ((const float4*)g)[tid];
    const float4 bv = ((const float4*)b)[tid];
    bf16x4 o4;
    o4[0] = (bf16_t)((v.x - mean) * rs * gv.x + bv.x);
    o4[1] = (bf16_t)((v.y - mean) * rs * gv.y + bv.y);
    o4[2] = (bf16_t)((v.z - mean) * rs * gv.z + bv.z);
    o4[3] = (bf16_t)((v.w - mean) * rs * gv.w + bv.w);
    ((bf16x4*)(out + (size_t)row * Dd))[tid] = o4;
}

// =====================  GEMM: C[M,N] = A[M,K](bf16) @ Bt[N,K](bf16) + bias ==
// EPI 0: bf16 out [M,N];  EPI 1: f32 out = acc+bias+resid;  EPI 2: vT out
template <int EPI>
__global__ __launch_bounds__(256)
void gemm_bt(const bf16_t* __restrict__ A, const bf16_t* __restrict__ Bt,
             const float* __restrict__ bias, const float* __restrict__ resid,
             void* __restrict__ outp, int M, int N, int K) {
    __shared__ bf16_t As[128 * 64];
    __shared__ bf16_t Bs[128 * 64];
    const int tid = threadIdx.x;
    const int lane = tid & 63;
    const int wave = tid >> 6;
    const int wr = wave >> 1, wc = wave & 1;          // 2x2 waves, 64x64 each
    const int m0 = blockIdx.y * 128, n0 = blockIdx.x * 128;
    const int lr = lane & 15, lg = lane >> 4;

    const f32x4 z0 = {0.f, 0.f, 0.f, 0.f};
    f32x4 acc[4][4];
#pragma unroll
    for (int i = 0; i < 4; ++i)
#pragma unroll
        for (int j = 0; j < 4; ++j) acc[i][j] = z0;

    for (int k0 = 0; k0 < K; k0 += 64) {
#pragma unroll
        for (int c = 0; c < 4; ++c) {
            const int lin = c * 256 + tid;
            const int row = lin >> 3, col = (lin & 7) * 8;
            g2l16(A + (size_t)(m0 + row) * K + k0 + col, (char*)As + lin * 16);
        }
#pragma unroll
        for (int c = 0; c < 4; ++c) {
            const int lin = c * 256 + tid;
            const int row = lin >> 3, col = (lin & 7) * 8;
            g2l16(Bt + (size_t)(n0 + row) * K + k0 + col, (char*)Bs + lin * 16);
        }
        __syncthreads();

        bf16x8 af[2][4], bw[2][4];
#pragma unroll
        for (int kk = 0; kk < 2; ++kk)
#pragma unroll
            for (int mi = 0; mi < 4; ++mi)
                af[kk][mi] = *(const bf16x8*)(As + (wr * 64 + mi * 16 + lr) * 64 +
                                              kk * 32 + lg * 8);
#pragma unroll
        for (int kk = 0; kk < 2; ++kk)
#pragma unroll
            for (int ni = 0; ni < 4; ++ni)
                bw[kk][ni] = *(const bf16x8*)(Bs + (wc * 64 + ni * 16 + lr) * 64 +
                                              kk * 32 + lg * 8);
#pragma unroll
        for (int mi = 0; mi < 4; ++mi)
#pragma unroll
            for (int ni = 0; ni < 4; ++ni) {
                acc[mi][ni] = __builtin_amdgcn_mfma_f32_16x16x32_bf16(
                    af[0][mi], bw[0][ni], acc[mi][ni], 0, 0, 0);
                acc[mi][ni] = __builtin_amdgcn_mfma_f32_16x16x32_bf16(
                    af[1][mi], bw[1][ni], acc[mi][ni], 0, 0, 0);
            }
        __syncthreads();
    }

    // epilogue: D row=(lane>>4)*4+r, col=lane&15 (m89-verified)
#pragma unroll
    for (int mi = 0; mi < 4; ++mi) {
#pragma unroll
        for (int ni = 0; ni < 4; ++ni) {
            const int gc = n0 + wc * 64 + ni * 16 + lr;
            const int gr0 = m0 + wr * 64 + mi * 16 + lg * 4;
            const float bvl = bias[gc];
#pragma unroll
            for (int r = 0; r < 4; ++r) {
                const int gr = gr0 + r;
                const float val = acc[mi][ni][r] + bvl;
                if constexpr (EPI == 0) {
                    ((bf16_t*)outp)[(size_t)gr * N + gc] = (bf16_t)val;
                } else if constexpr (EPI == 1) {
                    const size_t idx = (size_t)gr * N + gc;
                    ((float*)outp)[idx] = val + resid[idx];
                } else {
                    // vT[b, hd=gc, s]  (token gr = b*2048 + s)
                    const int bb = gr >> 11, sS = gr & 2047;
                    ((bf16_t*)outp)[((size_t)bb << 21) + ((size_t)gc << 11) + sS] =
                        (bf16_t)val;
                }
            }
        }
    }
}

// =====================  fused attention  =====================
// block = 4 waves; block handles (b, h, 64 q-rows); wave handles 16 q-rows.
// pass A: online row max/sumexp (scores discarded). pass B: recompute scores,
// write attn (coalesced via LDS bounce), accumulate ctx = P @ V (vT layout).
__global__ __launch_bounds__(256)
void attn_fused(const bf16_t* __restrict__ q, const bf16_t* __restrict__ k,
                const bf16_t* __restrict__ vT, float* __restrict__ attn,
                bf16_t* __restrict__ ctx) {
    __shared__ float P[4][16][68];   // per-wave P tile, padded
    const int tid = threadIdx.x, lane = tid & 63, wave = tid >> 6;
    const int lr = lane & 15, lg = lane >> 4;
    const int blk = blockIdx.x;
    const int qc = blk & 31, bh = blk >> 5;
    const int b = bh >> 4, h = bh & 15;
    const int q0 = qc * 64 + wave * 16;
    const size_t base = (size_t)b * Ss * 1024 + h * 64;
    constexpr float SC = 0.125f;                    // 1/sqrt(64)
    constexpr float L2E = 1.4426950408889634f;
    const f32x4 z0 = {0.f, 0.f, 0.f, 0.f};

    bf16x8 aq[2];
#pragma unroll
    for (int kk = 0; kk < 2; ++kk)
        aq[kk] = *(const bf16x8*)(q + base + (size_t)(q0 + lr) * 1024 + kk * 32 + lg * 8);

    float m[4] = {-1e30f, -1e30f, -1e30f, -1e30f};
    float l[4] = {0.f, 0.f, 0.f, 0.f};

    // ---- pass A: running max / sum ----
    for (int kt = 0; kt < Ss / 64; ++kt) {
        f32x4 sa[4];
#pragma unroll
        for (int ct = 0; ct < 4; ++ct) {
            const size_t krow = base + (size_t)(kt * 64 + ct * 16 + lr) * 1024;
            bf16x8 b0 = *(const bf16x8*)(k + krow + lg * 8);
            bf16x8 b1 = *(const bf16x8*)(k + krow + 32 + lg * 8);
            sa[ct] = __builtin_amdgcn_mfma_f32_16x16x32_bf16(aq[0], b0, z0, 0, 0, 0);
            sa[ct] = __builtin_amdgcn_mfma_f32_16x16x32_bf16(aq[1], b1, sa[ct], 0, 0, 0);
        }
#pragma unroll
        for (int r = 0; r < 4; ++r) {
            float tm = fmaxf(fmaxf(sa[0][r], sa[1][r]), fmaxf(sa[2][r], sa[3][r])) * SC;
#pragma unroll
            for (int o = 1; o < 16; o <<= 1) tm = fmaxf(tm, __shfl_xor(tm, o));
            const float mn = fmaxf(m[r], tm);
            float e = 0.f;
#pragma unroll
            for (int ct = 0; ct < 4; ++ct) e += exp2f((sa[ct][r] * SC - mn) * L2E);
#pragma unroll
            for (int o = 1; o < 16; o <<= 1) e += __shfl_xor(e, o);
            l[r] = l[r] * exp2f((m[r] - mn) * L2E) + e;
            m[r] = mn;
        }
    }
    float invl[4];
#pragma unroll
    for (int r = 0; r < 4; ++r) invl[r] = 1.f / l[r];

    f32x4 cacc[4];
#pragma unroll
    for (int nd = 0; nd < 4; ++nd) cacc[nd] = z0;

    // ---- pass B: recompute, normalize, write attn, PV ----
    for (int kt = 0; kt < Ss / 64; ++kt) {
#pragma unroll
        for (int ct = 0; ct < 4; ++ct) {
            const size_t krow = base + (size_t)(kt * 64 + ct * 16 + lr) * 1024;
            bf16x8 b0 = *(const bf16x8*)(k + krow + lg * 8);
            bf16x8 b1 = *(const bf16x8*)(k + krow + 32 + lg * 8);
            f32x4 sb = __builtin_amdgcn_mfma_f32_16x16x32_bf16(aq[0], b0, z0, 0, 0, 0);
            sb = __builtin_amdgcn_mfma_f32_16x16x32_bf16(aq[1], b1, sb, 0, 0, 0);
#pragma unroll
            for (int r = 0; r < 4; ++r)
                P[wave][lg * 4 + r][ct * 16 + lr] =
                    exp2f((sb[r] * SC - m[r]) * L2E) * invl[r];
        }
        // coalesced attn write: 4 instrs, each 4 rows x 256B contiguous
#pragma unroll
        for (int u = 0; u < 4; ++u) {
            const int rl = u * 4 + lg;
            float4 val = *(const float4*)&P[wave][rl][lr * 4];
            *(float4*)(attn + ((size_t)bh * Ss + q0 + rl) * Ss + kt * 64 + lr * 4) = val;
        }
        // PV: A = P tile (bf16), B = vT rows (contiguous along s)
#pragma unroll
        for (int kst = 0; kst < 2; ++kst) {
            bf16x8 pa;
#pragma unroll
            for (int j = 0; j < 8; ++j)
                pa[j] = (bf16_t)P[wave][lr][kst * 32 + lg * 8 + j];
#pragma unroll
            for (int nd = 0; nd < 4; ++nd) {
                bf16x8 vb = *(const bf16x8*)(vT + ((size_t)bh * 64 + nd * 16 + lr) * Ss +
                                             kt * 64 + kst * 32 + lg * 8);
                cacc[nd] = __builtin_amdgcn_mfma_f32_16x16x32_bf16(pa, vb, cacc[nd], 0, 0, 0);
            }
        }
    }
    // ctx write [token, h*64+dk] bf16
#pragma unroll
    for (int nd = 0; nd < 4; ++nd)
#pragma unroll
        for (int r = 0; r < 4; ++r)
            ctx[((size_t)b * Ss + q0 + lg * 4 + r) * 1024 + h * 64 + nd * 16 + lr] =
                (bf16_t)cacc[nd][r];
}

// =====================  GeGLU elementwise (exact gelu)  =====================
__global__ __launch_bounds__(256)
void geglu_kernel(const bf16_t* __restrict__ hg, const bf16_t* __restrict__ hl,
                  bf16_t* __restrict__ g) {
    const size_t i = ((size_t)blockIdx.x * 256 + threadIdx.x) * 8;
    bf16x8 a = *(const bf16x8*)(hg + i);
    bf16x8 c = *(const bf16x8*)(hl + i);
    bf16x8 o;
#pragma unroll
    for (int j = 0; j < 8; ++j) {
        const float x = (float)a[j];
        const float y = (float)c[j];
        const float ge = 0.5f * x * (1.f + erff(x * 0.70710678118654752f));
        o[j] = (bf16_t)(ge * y);
    }
    *(bf16x8*)(g + i) = o;
}

// =====================  launcher  =====================
extern "C" void kernel_launch(void* const* d_in, const int* in_sizes, int n_in,
                              void* d_out, int out_size, void* d_ws, size_t ws_size,
                              hipStream_t stream) {
    const float* inp  = (const float*)d_in[0];
    const float* wq   = (const float*)d_in[1];
    const float* bq   = (const float*)d_in[2];
    const float* wk   = (const float*)d_in[3];
    const float* bk   = (const float*)d_in[4];
    const float* wv   = (const float*)d_in[5];
    const float* bv   = (const float*)d_in[6];
    const float* wo   = (const float*)d_in[7];
    const float* bo   = (const float*)d_in[8];
    const float* ln1g = (const float*)d_in[9];
    const float* ln1b = (const float*)d_in[10];
    const float* wi0  = (const float*)d_in[11];
    const float* bi0  = (const float*)d_in[12];
    const float* wi1  = (const float*)d_in[13];
    const float* bi1  = (const float*)d_in[14];
    const float* wff  = (const float*)d_in[15];
    const float* bff  = (const float*)d_in[16];
    const float* ln2g = (const float*)d_in[17];
    const float* ln2b = (const float*)d_in[18];

    // ---- workspace layout (152 MiB) ----
    const size_t M1 = 1u << 20;
    bf16_t* wsb  = (bf16_t*)d_ws;
    bf16_t* wqT  = wsb + 0 * M1;
    bf16_t* wkT  = wsb + 1 * M1;
    bf16_t* wvT  = wsb + 2 * M1;
    bf16_t* woT  = wsb + 3 * M1;
    bf16_t* wi0T = wsb + 4 * M1;
    bf16_t* wi1T = wsb + 8 * M1;
    bf16_t* wffT = wsb + 12 * M1;
    bf16_t* hbuf = wsb + 16 * M1;            // 4M bf16 (ln1 out, reused for ln2 out)
    bf16_t* qbuf = hbuf + 4 * M1;
    bf16_t* kbuf = qbuf + 4 * M1;
    bf16_t* vTb  = kbuf + 4 * M1;            // [B,H,DK,S]
    bf16_t* ctxb = vTb + 4 * M1;
    float*  h1   = (float*)(ctxb + 4 * M1);  // 4M f32
    bf16_t* hg   = (bf16_t*)(h1 + 4 * M1);   // 16M bf16
    bf16_t* hl   = hg + 16 * M1;             // 16M bf16

    float* out  = (float*)d_out;
    float* attn = out + (size_t)TOK * Dd;    // +4,194,304 floats

    // 1) weights -> bf16 transposed [N,K]
    transpose_cast<<<dim3(1024 / 32, 1024 / 32), 256, 0, stream>>>(wq, wqT, 1024, 1024);
    transpose_cast<<<dim3(1024 / 32, 1024 / 32), 256, 0, stream>>>(wk, wkT, 1024, 1024);
    transpose_cast<<<dim3(1024 / 32, 1024 / 32), 256, 0, stream>>>(wv, wvT, 1024, 1024);
    transpose_cast<<<dim3(1024 / 32, 1024 / 32), 256, 0, stream>>>(wo, woT, 1024, 1024);
    transpose_cast<<<dim3(4096 / 32, 1024 / 32), 256, 0, stream>>>(wi0, wi0T, 1024, 4096);
    transpose_cast<<<dim3(4096 / 32, 1024 / 32), 256, 0, stream>>>(wi1, wi1T, 1024, 4096);
    transpose_cast<<<dim3(1024 / 32, 4096 / 32), 256, 0, stream>>>(wff, wffT, 4096, 1024);

    // 2) LN1
    ln_fwd<<<TOK, 256, 0, stream>>>(inp, ln1g, ln1b, hbuf);

    // 3) QKV projections
    gemm_bt<0><<<dim3(8, 32), 256, 0, stream>>>(hbuf, wqT, bq, nullptr, qbuf, TOK, 1024, 1024);
    gemm_bt<0><<<dim3(8, 32), 256, 0, stream>>>(hbuf, wkT, bk, nullptr, kbuf, TOK, 1024, 1024);
    gemm_bt<2><<<dim3(8, 32), 256, 0, stream>>>(hbuf, wvT, bv, nullptr, vTb, TOK, 1024, 1024);

    // 4) fused attention (writes attn region of d_out + ctx)
    attn_fused<<<Bb * Hh * (Ss / 64), 256, 0, stream>>>(qbuf, kbuf, vTb, attn, ctxb);

    // 5) output projection + residual -> h1 (f32)
    gemm_bt<1><<<dim3(8, 32), 256, 0, stream>>>(ctxb, woT, bo, inp, h1, TOK, 1024, 1024);

    // 6) LN2
    ln_fwd<<<TOK, 256, 0, stream>>>(h1, ln2g, ln2b, hbuf);

    // 7) FFN up projections
    gemm_bt<0><<<dim3(32, 32), 256, 0, stream>>>(hbuf, wi0T, bi0, nullptr, hg, TOK, 4096, 1024);
    gemm_bt<0><<<dim3(32, 32), 256, 0, stream>>>(hbuf, wi1T, bi1, nullptr, hl, TOK, 4096, 1024);

    // 8) GeGLU (g written over hg)
    geglu_kernel<<<8192, 256, 0, stream>>>(hg, hl, hg);

    // 9) down projection + residual -> out (f32)
    gemm_bt<1><<<dim3(8, 32), 256, 0, stream>>>(hg, wffT, bff, h1, out, TOK, 1024, 4096);
}

// Round 2
// 785.483 us; speedup vs baseline: 1.0802x; 1.0802x over previous
//
#include <hip/hip_runtime.h>
#include <hip/hip_bf16.h>
#include <cstdint>

#define DEV __device__ __forceinline__

typedef __bf16 bf16_t;
typedef __bf16 bf16x8 __attribute__((ext_vector_type(8)));
typedef __bf16 bf16x4 __attribute__((ext_vector_type(4)));
typedef float  f32x4  __attribute__((ext_vector_type(4)));

constexpr int Bb = 2, Ss = 2048, Dd = 1024, Hh = 16, DKk = 64, FFf = 4096;
constexpr int TOK = Bb * Ss;          // 4096 tokens
constexpr float LN_EPS = 1e-6f;

// ---- async global->LDS, 16B per lane (wave-uniform base + lane*16) ----
DEV void g2l16(const void* g, void* l) {
    __builtin_amdgcn_global_load_lds(
        (const __attribute__((address_space(1))) unsigned int*)g,
        (__attribute__((address_space(3))) unsigned int*)l, 16, 0, 0);
}

// =====================  weight fp32 [K,N] -> bf16 [N,K]  =====================
__global__ __launch_bounds__(256)
void transpose_cast(const float* __restrict__ src, bf16_t* __restrict__ dst,
                    int K, int N) {
    __shared__ float t[32][33];
    const int tx = threadIdx.x & 31, ty = threadIdx.x >> 5;
    const int n0 = blockIdx.x * 32, k0 = blockIdx.y * 32;
#pragma unroll
    for (int i = 0; i < 4; ++i)
        t[ty + 8 * i][tx] = src[(size_t)(k0 + ty + 8 * i) * N + n0 + tx];
    __syncthreads();
#pragma unroll
    for (int i = 0; i < 4; ++i)
        dst[(size_t)(n0 + ty + 8 * i) * K + k0 + tx] = (bf16_t)t[tx][ty + 8 * i];
}

// =====================  bias concat helpers  =====================
__global__ __launch_bounds__(256)
void concat3(const float* __restrict__ a, const float* __restrict__ b,
             const float* __restrict__ c, float* __restrict__ o) {
    const int i = blockIdx.x * 256 + threadIdx.x;   // grid 4 -> 1024 threads
    o[i] = a[i]; o[1024 + i] = b[i]; o[2048 + i] = c[i];
}
__global__ __launch_bounds__(256)
void concat2(const float* __restrict__ a, const float* __restrict__ b,
             float* __restrict__ o) {
    const int i = blockIdx.x * 256 + threadIdx.x;   // grid 16 -> 4096 threads
    o[i] = a[i]; o[4096 + i] = b[i];
}

// =====================  LayerNorm fp32 -> bf16  =====================
__global__ __launch_bounds__(256)
void ln_fwd(const float* __restrict__ x, const float* __restrict__ g,
            const float* __restrict__ b, bf16_t* __restrict__ out) {
    __shared__ float red[8];
    const int row = blockIdx.x, tid = threadIdx.x;
    const float4 v = ((const float4*)(x + (size_t)row * Dd))[tid];
    float s  = v.x + v.y + v.z + v.w;
    float sq = v.x * v.x + v.y * v.y + v.z * v.z + v.w * v.w;
#pragma unroll
    for (int o = 32; o; o >>= 1) { s += __shfl_xor(s, o); sq += __shfl_xor(sq, o); }
    if ((tid & 63) == 0) { red[tid >> 6] = s; red[4 + (tid >> 6)] = sq; }
    __syncthreads();
    s  = red[0] + red[1] + red[2] + red[3];
    sq = red[4] + red[5] + red[6] + red[7];
    const float mean = s * (1.f / Dd);
    const float var  = sq * (1.f / Dd) - mean * mean;
    const float rs   = rsqrtf(var + LN_EPS);
    const float4 gv = ((const float4*)g)[tid];
    const float4 bv = ((const float4*)b)[tid];
    bf16x4 o4;
    o4[0] = (bf16_t)((v.x - mean) * rs * gv.x + bv.x);
    o4[1] = (bf16_t)((v.y - mean) * rs * gv.y + bv.y);
    o4[2] = (bf16_t)((v.z - mean) * rs * gv.z + bv.z);
    o4[3] = (bf16_t)((v.w - mean) * rs * gv.w + bv.w);
    ((bf16x4*)(out + (size_t)row * Dd))[tid] = o4;
}

// =====================  GEMM: C[M,N] = A[M,K](bf16) @ Bt[N,K](bf16) + bias ==
// EPI 0: bf16 out [M,N]
// EPI 1: f32 out = acc + bias + resid
// EPI 3: fused QKV epilogue: n<1024 -> q rows, <2048 -> k rows, else vT
template <int EPI>
__global__ __launch_bounds__(256)
void gemm_bt(const bf16_t* __restrict__ A, const bf16_t* __restrict__ Bt,
             const float* __restrict__ bias, const float* __restrict__ resid,
             void* __restrict__ outp, void* __restrict__ out2,
             void* __restrict__ out3, int M, int N, int K) {
    __shared__ bf16_t As[128 * 64];
    __shared__ bf16_t Bs[128 * 64];
    const int tid = threadIdx.x;
    const int lane = tid & 63;
    const int wave = tid >> 6;
    const int wr = wave >> 1, wc = wave & 1;          // 2x2 waves, 64x64 each
    const int m0 = blockIdx.y * 128, n0 = blockIdx.x * 128;
    const int lr = lane & 15, lg = lane >> 4;

    const f32x4 z0 = {0.f, 0.f, 0.f, 0.f};
    f32x4 acc[4][4];
#pragma unroll
    for (int i = 0; i < 4; ++i)
#pragma unroll
        for (int j = 0; j < 4; ++j) acc[i][j] = z0;

    for (int k0 = 0; k0 < K; k0 += 64) {
#pragma unroll
        for (int c = 0; c < 4; ++c) {
            const int lin = c * 256 + tid;
            const int row = lin >> 3, col = (lin & 7) * 8;
            g2l16(A + (size_t)(m0 + row) * K + k0 + col, (char*)As + lin * 16);
        }
#pragma unroll
        for (int c = 0; c < 4; ++c) {
            const int lin = c * 256 + tid;
            const int row = lin >> 3, col = (lin & 7) * 8;
            g2l16(Bt + (size_t)(n0 + row) * K + k0 + col, (char*)Bs + lin * 16);
        }
        __syncthreads();

        bf16x8 af[2][4], bw[2][4];
#pragma unroll
        for (int kk = 0; kk < 2; ++kk)
#pragma unroll
            for (int mi = 0; mi < 4; ++mi)
                af[kk][mi] = *(const bf16x8*)(As + (wr * 64 + mi * 16 + lr) * 64 +
                                              kk * 32 + lg * 8);
#pragma unroll
        for (int kk = 0; kk < 2; ++kk)
#pragma unroll
            for (int ni = 0; ni < 4; ++ni)
                bw[kk][ni] = *(const bf16x8*)(Bs + (wc * 64 + ni * 16 + lr) * 64 +
                                              kk * 32 + lg * 8);
#pragma unroll
        for (int mi = 0; mi < 4; ++mi)
#pragma unroll
            for (int ni = 0; ni < 4; ++ni) {
                acc[mi][ni] = __builtin_amdgcn_mfma_f32_16x16x32_bf16(
                    af[0][mi], bw[0][ni], acc[mi][ni], 0, 0, 0);
                acc[mi][ni] = __builtin_amdgcn_mfma_f32_16x16x32_bf16(
                    af[1][mi], bw[1][ni], acc[mi][ni], 0, 0, 0);
            }
        __syncthreads();
    }

    // epilogue: D row=(lane>>4)*4+r, col=lane&15 (m89-verified)
#pragma unroll
    for (int mi = 0; mi < 4; ++mi) {
#pragma unroll
        for (int ni = 0; ni < 4; ++ni) {
            const int gc = n0 + wc * 64 + ni * 16 + lr;
            const int gr0 = m0 + wr * 64 + mi * 16 + lg * 4;
            const float bvl = bias[gc];
#pragma unroll
            for (int r = 0; r < 4; ++r) {
                const int gr = gr0 + r;
                const float val = acc[mi][ni][r] + bvl;
                if constexpr (EPI == 0) {
                    ((bf16_t*)outp)[(size_t)gr * N + gc] = (bf16_t)val;
                } else if constexpr (EPI == 1) {
                    const size_t idx = (size_t)gr * N + gc;
                    ((float*)outp)[idx] = val + resid[idx];
                } else {
                    const int sel = gc >> 10, col = gc & 1023;
                    if (sel == 0) {
                        ((bf16_t*)outp)[(size_t)gr * 1024 + col] = (bf16_t)val;
                    } else if (sel == 1) {
                        ((bf16_t*)out2)[(size_t)gr * 1024 + col] = (bf16_t)val;
                    } else {
                        const int bb = gr >> 11, sS = gr & 2047;
                        ((bf16_t*)out3)[((size_t)bb << 21) + ((size_t)col << 11) + sS] =
                            (bf16_t)val;
                    }
                }
            }
        }
    }
}

// =====================  fused attention (swapped-operand QK^T)  =============
// block = 4 independent waves; wave handles 16 q-rows. No barriers at all.
// Swapped mfma(K,Q): lane holds scores[q = q0+lr][k = kt*64+ct*16+lg*4+r]
// -> softmax row-reduce is in-lane tree + 2 shuffles (xor16, xor32).
__global__ __launch_bounds__(256)
void attn_fused(const bf16_t* __restrict__ q, const bf16_t* __restrict__ k,
                const bf16_t* __restrict__ vT, float* __restrict__ attn,
                bf16_t* __restrict__ ctx) {
    __shared__ float P[4][16][68];   // per-wave P tile, padded
    const int tid = threadIdx.x, lane = tid & 63, wave = tid >> 6;
    const int lr = lane & 15, lg = lane >> 4;
    int blk = blockIdx.x;
    blk = (blk & 7) * 128 + (blk >> 3);      // XCD swizzle (1024 % 8 == 0)
    const int qc = blk & 31, bh = blk >> 5;
    const int b = bh >> 4, h = bh & 15;
    const int q0 = qc * 64 + wave * 16;
    const size_t base = (size_t)b * (Ss * 1024) + h * 64;
    constexpr float SCL = 0.125f * 1.4426950408889634f;   // 1/sqrt(64) * log2(e)
    const f32x4 z0 = {0.f, 0.f, 0.f, 0.f};

    const bf16x8 aq0 = *(const bf16x8*)(q + base + (size_t)(q0 + lr) * 1024 + lg * 8);
    const bf16x8 aq1 = *(const bf16x8*)(q + base + (size_t)(q0 + lr) * 1024 + 32 + lg * 8);

    const bf16_t* kb = k + base;
    float m2 = -1e30f, l = 0.f;   // log2-domain running max / sum

    // ---- pass A: running max / sum (in-lane) ----
    for (int kt = 0; kt < Ss / 64; ++kt) {
        f32x4 sa[4];
        __builtin_amdgcn_s_setprio(1);
#pragma unroll
        for (int ct = 0; ct < 4; ++ct) {
            const bf16_t* kr = kb + (size_t)(kt * 64 + ct * 16 + lr) * 1024;
            bf16x8 k0 = *(const bf16x8*)(kr + lg * 8);
            bf16x8 k1 = *(const bf16x8*)(kr + 32 + lg * 8);
            sa[ct] = __builtin_amdgcn_mfma_f32_16x16x32_bf16(k0, aq0, z0, 0, 0, 0);
            sa[ct] = __builtin_amdgcn_mfma_f32_16x16x32_bf16(k1, aq1, sa[ct], 0, 0, 0);
        }
        __builtin_amdgcn_s_setprio(0);
        float mt = fmaxf(
            fmaxf(fmaxf(fmaxf(sa[0][0], sa[0][1]), fmaxf(sa[0][2], sa[0][3])),
                  fmaxf(fmaxf(sa[1][0], sa[1][1]), fmaxf(sa[1][2], sa[1][3]))),
            fmaxf(fmaxf(fmaxf(sa[2][0], sa[2][1]), fmaxf(sa[2][2], sa[2][3])),
                  fmaxf(fmaxf(sa[3][0], sa[3][1]), fmaxf(sa[3][2], sa[3][3]))));
        mt = fmaxf(mt, __shfl_xor(mt, 16));
        mt = fmaxf(mt, __shfl_xor(mt, 32));
        const float mn2 = fmaxf(m2, mt * SCL);
        f32x4 e4 = z0;
#pragma unroll
        for (int ct = 0; ct < 4; ++ct)
#pragma unroll
            for (int r = 0; r < 4; ++r)
                e4[r] += exp2f(sa[ct][r] * SCL - mn2);
        float e = (e4[0] + e4[1]) + (e4[2] + e4[3]);
        e += __shfl_xor(e, 16);
        e += __shfl_xor(e, 32);
        l = l * exp2f(m2 - mn2) + e;
        m2 = mn2;
    }
    const float invl = 1.f / l;

    f32x4 cacc[4];
#pragma unroll
    for (int nd = 0; nd < 4; ++nd) cacc[nd] = z0;

    float* attn_base = attn + ((size_t)bh * Ss + q0) * Ss;

    // ---- pass B: recompute, normalize, write attn, PV ----
    for (int kt = 0; kt < Ss / 64; ++kt) {
        __builtin_amdgcn_s_setprio(1);
#pragma unroll
        for (int ct = 0; ct < 4; ++ct) {
            const bf16_t* kr = kb + (size_t)(kt * 64 + ct * 16 + lr) * 1024;
            bf16x8 k0 = *(const bf16x8*)(kr + lg * 8);
            bf16x8 k1 = *(const bf16x8*)(kr + 32 + lg * 8);
            f32x4 sb = __builtin_amdgcn_mfma_f32_16x16x32_bf16(k0, aq0, z0, 0, 0, 0);
            sb = __builtin_amdgcn_mfma_f32_16x16x32_bf16(k1, aq1, sb, 0, 0, 0);
            float4 p;
            p.x = exp2f(sb[0] * SCL - m2) * invl;
            p.y = exp2f(sb[1] * SCL - m2) * invl;
            p.z = exp2f(sb[2] * SCL - m2) * invl;
            p.w = exp2f(sb[3] * SCL - m2) * invl;
            *(float4*)&P[wave][lr][ct * 16 + lg * 4] = p;   // float4, conflict-spread
        }
        __builtin_amdgcn_s_setprio(0);
        // attn write: 4 instrs, each 4 rows x 256B contiguous
#pragma unroll
        for (int u = 0; u < 4; ++u) {
            const int rl = u * 4 + lg;
            const float4 val = *(const float4*)&P[wave][rl][lr * 4];
            *(float4*)(attn_base + (size_t)rl * Ss + kt * 64 + lr * 4) = val;
        }
        // PV: A = P rows (lr = q-row), B = vT rows (contiguous along s)
        __builtin_amdgcn_s_setprio(1);
#pragma unroll
        for (int kst = 0; kst < 2; ++kst) {
            const float* pr = &P[wave][lr][kst * 32 + lg * 8];
            bf16x8 pa;
#pragma unroll
            for (int j = 0; j < 8; ++j) pa[j] = (bf16_t)pr[j];
#pragma unroll
            for (int nd = 0; nd < 4; ++nd) {
                bf16x8 vb = *(const bf16x8*)(vT + ((size_t)bh * 64 + nd * 16 + lr) * Ss +
                                             kt * 64 + kst * 32 + lg * 8);
                cacc[nd] = __builtin_amdgcn_mfma_f32_16x16x32_bf16(pa, vb, cacc[nd], 0, 0, 0);
            }
        }
        __builtin_amdgcn_s_setprio(0);
    }
    // ctx write [token, h*64+dk] bf16
#pragma unroll
    for (int nd = 0; nd < 4; ++nd)
#pragma unroll
        for (int r = 0; r < 4; ++r)
            ctx[((size_t)b * Ss + q0 + lg * 4 + r) * 1024 + h * 64 + nd * 16 + lr] =
                (bf16_t)cacc[nd][r];
}

// =====================  GeGLU elementwise (exact gelu)  =====================
// reads fused [4096][8192] (gate | linear), writes [4096][4096]
__global__ __launch_bounds__(256)
void geglu_kernel(const bf16_t* __restrict__ hgl, bf16_t* __restrict__ g) {
    const int row = blockIdx.y;
    const int c = (blockIdx.x * 256 + threadIdx.x) * 8;
    const size_t rb = (size_t)row * 8192;
    bf16x8 a  = *(const bf16x8*)(hgl + rb + c);
    bf16x8 cc = *(const bf16x8*)(hgl + rb + 4096 + c);
    bf16x8 o;
#pragma unroll
    for (int j = 0; j < 8; ++j) {
        const float x = (float)a[j];
        const float y = (float)cc[j];
        o[j] = (bf16_t)(0.5f * x * (1.f + erff(x * 0.70710678118654752f)) * y);
    }
    *(bf16x8*)(g + (size_t)row * 4096 + c) = o;
}

// =====================  launcher  =====================
extern "C" void kernel_launch(void* const* d_in, const int* in_sizes, int n_in,
                              void* d_out, int out_size, void* d_ws, size_t ws_size,
                              hipStream_t stream) {
    const float* inp  = (const float*)d_in[0];
    const float* wq   = (const float*)d_in[1];
    const float* bq   = (const float*)d_in[2];
    const float* wk   = (const float*)d_in[3];
    const float* bk   = (const float*)d_in[4];
    const float* wv   = (const float*)d_in[5];
    const float* bv   = (const float*)d_in[6];
    const float* wo   = (const float*)d_in[7];
    const float* bo   = (const float*)d_in[8];
    const float* ln1g = (const float*)d_in[9];
    const float* ln1b = (const float*)d_in[10];
    const float* wi0  = (const float*)d_in[11];
    const float* bi0  = (const float*)d_in[12];
    const float* wi1  = (const float*)d_in[13];
    const float* bi1  = (const float*)d_in[14];
    const float* wff  = (const float*)d_in[15];
    const float* bff  = (const float*)d_in[16];
    const float* ln2g = (const float*)d_in[17];
    const float* ln2b = (const float*)d_in[18];

    // ---- workspace layout (152 MiB, same proven footprint as round 1) ----
    const size_t M1 = 1u << 20;
    bf16_t* wsb  = (bf16_t*)d_ws;
    bf16_t* wqT  = wsb + 0 * M1;             // 3M contiguous: fused QKV weights
    bf16_t* wkT  = wsb + 1 * M1;
    bf16_t* wvT  = wsb + 2 * M1;
    bf16_t* woT  = wsb + 3 * M1;
    bf16_t* wi0T = wsb + 4 * M1;             // 8M contiguous: fused FFN weights
    bf16_t* wi1T = wsb + 8 * M1;
    bf16_t* wffT = wsb + 12 * M1;
    bf16_t* hbuf = wsb + 16 * M1;            // LN out (4M)
    bf16_t* qbuf = wsb + 20 * M1;
    bf16_t* kbuf = wsb + 24 * M1;
    bf16_t* vTb  = wsb + 28 * M1;            // [B,H,DK,S]
    bf16_t* ctxb = wsb + 32 * M1;
    float*  h1   = (float*)(wsb + 36 * M1);  // 4M f32 (ends at 44M slots)
    bf16_t* hgl  = wsb + 44 * M1;            // fused FFN out [4096][8192] (32M)
    bf16_t* gbuf = wsb + 20 * M1;            // geglu out, reuses qbuf..ctx (16M)
    float*  cb   = (float*)(wsb + 32 * M1);  // qkv bias concat: ctx region, pre-attn
    float*  cb2  = (float*)(wsb + 32 * M1);  // ffn bias concat: ctx region, post-wo

    float* out  = (float*)d_out;
    float* attn = out + (size_t)TOK * Dd;

    // 1) weights -> bf16 transposed [N,K]
    transpose_cast<<<dim3(1024 / 32, 1024 / 32), 256, 0, stream>>>(wq, wqT, 1024, 1024);
    transpose_cast<<<dim3(1024 / 32, 1024 / 32), 256, 0, stream>>>(wk, wkT, 1024, 1024);
    transpose_cast<<<dim3(1024 / 32, 1024 / 32), 256, 0, stream>>>(wv, wvT, 1024, 1024);
    transpose_cast<<<dim3(1024 / 32, 1024 / 32), 256, 0, stream>>>(wo, woT, 1024, 1024);
    transpose_cast<<<dim3(4096 / 32, 1024 / 32), 256, 0, stream>>>(wi0, wi0T, 1024, 4096);
    transpose_cast<<<dim3(4096 / 32, 1024 / 32), 256, 0, stream>>>(wi1, wi1T, 1024, 4096);
    transpose_cast<<<dim3(1024 / 32, 4096 / 32), 256, 0, stream>>>(wff, wffT, 4096, 1024);

    // 2) bias concat for fused QKV (into ctx region, consumed before attn)
    concat3<<<4, 256, 0, stream>>>(bq, bk, bv, cb);

    // 3) LN1
    ln_fwd<<<TOK, 256, 0, stream>>>(inp, ln1g, ln1b, hbuf);

    // 4) fused QKV projection (N=3072, 768 blocks = 3/CU)
    gemm_bt<3><<<dim3(24, 32), 256, 0, stream>>>(hbuf, wqT, cb, nullptr,
                                                 qbuf, kbuf, vTb, TOK, 3072, 1024);

    // 5) fused attention (writes attn region of d_out + ctx)
    attn_fused<<<Bb * Hh * (Ss / 64), 256, 0, stream>>>(qbuf, kbuf, vTb, attn, ctxb);

    // 6) output projection + residual -> h1 (f32)
    gemm_bt<1><<<dim3(8, 32), 256, 0, stream>>>(ctxb, woT, bo, inp, h1, nullptr, nullptr,
                                                TOK, 1024, 1024);

    // 7) bias concat for fused FFN (ctx region is free now)
    concat2<<<16, 256, 0, stream>>>(bi0, bi1, cb2);

    // 8) LN2
    ln_fwd<<<TOK, 256, 0, stream>>>(h1, ln2g, ln2b, hbuf);

    // 9) fused FFN up projection (N=8192, 2048 blocks = 8/CU)
    gemm_bt<0><<<dim3(64, 32), 256, 0, stream>>>(hbuf, wi0T, cb2, nullptr, hgl,
                                                 nullptr, nullptr, TOK, 8192, 1024);

    // 10) GeGLU -> gbuf
    geglu_kernel<<<dim3(2, 4096), 256, 0, stream>>>(hgl, gbuf);

    // 11) down projection + residual -> out (f32)
    gemm_bt<1><<<dim3(8, 32), 256, 0, stream>>>(gbuf, wffT, bff, h1, out, nullptr, nullptr,
                                                TOK, 1024, 4096);
}